// Round 1
// baseline (121.260 us; speedup 1.0000x reference)
//
#include <hip/hip_runtime.h>

#define NB 2048
#define NJ 22
#define ND 128

// out[b][i][j][e] = sum_d (src[b][j][d] - src[b][i][d]) * W[e][d] + bias[e]
//                 = Y[b][j][e] - Y[b][i][e] + bias[e],   Y = src @ W^T
__global__ __launch_bounds__(256, 4) void see_kernel(
    const float* __restrict__ src, const float* __restrict__ W,
    const float* __restrict__ bias, float* __restrict__ out) {
  __shared__ float srcS[NJ * ND];  // [j][d]
  __shared__ float YS[NJ * ND];    // [j][e]

  const int b = blockIdx.x;
  const int t = threadIdx.x;
  const float* srcB = src + (size_t)b * NJ * ND;

  // ---- stage src[b] -> LDS, coalesced float4 (704 float4s) ----
  for (int idx = t; idx < NJ * ND / 4; idx += 256) {
    reinterpret_cast<float4*>(srcS)[idx] =
        reinterpret_cast<const float4*>(srcB)[idx];
  }

  const int e  = t & 127;   // output feature this thread owns
  const int dh = t >> 7;    // which half of the d-range (0/1)

  // ---- W[e][dh*64 .. dh*64+63] into registers (L2-resident, 64 KB total) ----
  float w[64];
  {
    const float4* Wrow = reinterpret_cast<const float4*>(W + e * ND + dh * 64);
#pragma unroll
    for (int k = 0; k < 16; ++k) {
      float4 v = Wrow[k];
      w[4 * k + 0] = v.x;
      w[4 * k + 1] = v.y;
      w[4 * k + 2] = v.z;
      w[4 * k + 3] = v.w;
    }
  }
  __syncthreads();

  // ---- partial Y[j][e] over this thread's d-half; src via LDS broadcast ----
  float acc[NJ];
#pragma unroll
  for (int j = 0; j < NJ; ++j) {
    const float4* s4 = reinterpret_cast<const float4*>(srcS + j * ND + dh * 64);
    float a = 0.f;
#pragma unroll
    for (int k = 0; k < 16; ++k) {
      float4 s = s4[k];  // wave-uniform address -> LDS broadcast
      a += s.x * w[4 * k + 0];
      a += s.y * w[4 * k + 1];
      a += s.z * w[4 * k + 2];
      a += s.w * w[4 * k + 3];
    }
    acc[j] = a;
  }

  // ---- combine the two d-halves through LDS ----
  if (dh == 0) {
#pragma unroll
    for (int j = 0; j < NJ; ++j) YS[j * ND + e] = acc[j];
  }
  __syncthreads();
  if (dh == 1) {
#pragma unroll
    for (int j = 0; j < NJ; ++j) YS[j * ND + e] += acc[j];
  }
  __syncthreads();

  // ---- streaming expansion: out[b][i][j][e] = YS[j][e] - YS[i][e] + bias[e]
  // q walks (j, e4); e4 = q & 31 == t & 31 is thread-invariant (256 % 32 == 0).
  const int e4c = t & 31;
  const float4 bb4 = reinterpret_cast<const float4*>(bias)[e4c];
  float* outB = out + (size_t)b * NJ * NJ * ND;

  for (int ii = 0; ii < NJ; ++ii) {
    float4 yi = reinterpret_cast<const float4*>(YS + ii * ND)[e4c];
    float4 yib;  // bias - Y[i]
    yib.x = bb4.x - yi.x;
    yib.y = bb4.y - yi.y;
    yib.z = bb4.z - yi.z;
    yib.w = bb4.w - yi.w;
    float* outRow = outB + (size_t)ii * NJ * ND;
    for (int q = t; q < NJ * (ND / 4); q += 256) {  // 704 float4 per i-row
      int jx = q >> 5;
      float4 yj = reinterpret_cast<const float4*>(YS + jx * ND)[e4c];
      float4 r;
      r.x = yj.x + yib.x;
      r.y = yj.y + yib.y;
      r.z = yj.z + yib.z;
      r.w = yj.w + yib.w;
      reinterpret_cast<float4*>(outRow)[q] = r;
    }
  }
}

extern "C" void kernel_launch(void* const* d_in, const int* in_sizes, int n_in,
                              void* d_out, int out_size, void* d_ws, size_t ws_size,
                              hipStream_t stream) {
  const float* src  = (const float*)d_in[0];  // [2048, 22, 128] f32
  const float* W    = (const float*)d_in[1];  // [128, 128] f32, W[e][d]
  const float* bias = (const float*)d_in[2];  // [128] f32
  float* out = (float*)d_out;                 // [2048, 22, 22, 128] f32

  see_kernel<<<NB, 256, 0, stream>>>(src, W, bias, out);
}

// Round 3
// 111.407 us; speedup vs baseline: 1.0884x; 1.0884x over previous
//
#include <hip/hip_runtime.h>

#define NB 2048
#define NJ 22
#define ND 128
#define ROW4 (NJ * ND / 4)  // 704 float4 per i-row

typedef float f32x4 __attribute__((ext_vector_type(4)));

// out[b][i][j][e] = Y[b][j][e] - Y[b][i][e] + bias[e],  Y = src @ W^T
__global__ __launch_bounds__(256, 4) void see_kernel(
    const float* __restrict__ src, const float* __restrict__ W,
    const float* __restrict__ bias, float* __restrict__ out) {
  __shared__ float srcS[NJ * ND];  // [j][d]  (11 KB)
  __shared__ float YS[NJ * ND];    // [j][e]  (11 KB)

  const int b = blockIdx.x;
  const int t = threadIdx.x;
  const float* srcB = src + (size_t)b * NJ * ND;

  // ---- stage src[b] -> LDS, coalesced float4 ----
  for (int idx = t; idx < NJ * ND / 4; idx += 256) {
    reinterpret_cast<f32x4*>(srcS)[idx] =
        reinterpret_cast<const f32x4*>(srcB)[idx];
  }

  const int e  = t & 127;  // output feature this thread owns
  const int dh = t >> 7;   // d-half (0/1)

  // ---- W[e][dh*64 .. +63] into registers (64 KB total, L2-resident) ----
  float w[64];
  {
    const f32x4* Wrow = reinterpret_cast<const f32x4*>(W + e * ND + dh * 64);
#pragma unroll
    for (int k = 0; k < 16; ++k) {
      f32x4 v = Wrow[k];
      w[4 * k + 0] = v.x;
      w[4 * k + 1] = v.y;
      w[4 * k + 2] = v.z;
      w[4 * k + 3] = v.w;
    }
  }
  __syncthreads();  // B0: srcS ready

  // ---- Y in two chunks of 11 rows to keep VGPR pressure < 128 ----
  for (int c = 0; c < 2; ++c) {
    float acc[11];
#pragma unroll
    for (int jj = 0; jj < 11; ++jj) {
      const int j = c * 11 + jj;
      const f32x4* s4 = reinterpret_cast<const f32x4*>(srcS + j * ND + dh * 64);
      float a = 0.f;
#pragma unroll
      for (int k = 0; k < 16; ++k) {
        f32x4 s = s4[k];  // wave-uniform address -> LDS broadcast
        a += s.x * w[4 * k + 0];
        a += s.y * w[4 * k + 1];
        a += s.z * w[4 * k + 2];
        a += s.w * w[4 * k + 3];
      }
      acc[jj] = a;
    }
    if (dh == 0) {
#pragma unroll
      for (int jj = 0; jj < 11; ++jj) YS[(c * 11 + jj) * ND + e] = acc[jj];
    }
    __syncthreads();  // chunk's dh0 writes visible
    if (dh == 1) {
#pragma unroll
      for (int jj = 0; jj < 11; ++jj) YS[(c * 11 + jj) * ND + e] += acc[jj];
    }
    // next chunk touches disjoint YS rows -> no barrier needed here
  }
  __syncthreads();  // YS complete

  // ---- streaming expansion ----
  // Flat float4 index within an i-row: q = jx*32 + e4,  q = t + 256*k, k=0..2.
  // So this thread always writes rows {j0, j0+8, j0+16} at column e4.
  const int e4 = t & 31;
  const int j0 = t >> 5;  // 0..7
  const f32x4* YS4 = reinterpret_cast<const f32x4*>(YS);
  const f32x4 bb4 = reinterpret_cast<const f32x4*>(bias)[e4];

  f32x4 yj0 = YS4[j0 * 32 + e4];
  f32x4 yj1 = YS4[(j0 + 8) * 32 + e4];
  f32x4 yj2 = {0.f, 0.f, 0.f, 0.f};
  if (j0 < 6) yj2 = YS4[(j0 + 16) * 32 + e4];
  // fold bias once: out = (Y[j]+b) - Y[i]
  yj0 += bb4;
  yj1 += bb4;
  yj2 += bb4;

  f32x4* outB4 = reinterpret_cast<f32x4*>(out + (size_t)b * NJ * NJ * ND);

  for (int ii = 0; ii < NJ; ++ii) {
    f32x4 yi = YS4[ii * 32 + e4];  // 512B row read, 2x broadcast across wave
    f32x4* outRow4 = outB4 + (size_t)ii * ROW4;
    f32x4 r0 = yj0 - yi;
    f32x4 r1 = yj1 - yi;
    __builtin_nontemporal_store(r0, outRow4 + t);
    __builtin_nontemporal_store(r1, outRow4 + t + 256);
    if (j0 < 6) {
      f32x4 r2 = yj2 - yi;
      __builtin_nontemporal_store(r2, outRow4 + t + 512);
    }
  }
}

extern "C" void kernel_launch(void* const* d_in, const int* in_sizes, int n_in,
                              void* d_out, int out_size, void* d_ws, size_t ws_size,
                              hipStream_t stream) {
  const float* src  = (const float*)d_in[0];  // [2048, 22, 128] f32
  const float* W    = (const float*)d_in[1];  // [128, 128] f32, W[e][d]
  const float* bias = (const float*)d_in[2];  // [128] f32
  float* out = (float*)d_out;                 // [2048, 22, 22, 128] f32

  see_kernel<<<NB, 256, 0, stream>>>(src, W, bias, out);
}